// Round 7
// baseline (1049.941 us; speedup 1.0000x reference)
//
#include <hip/hip_runtime.h>
#include <hip/hip_bf16.h>

// HybridSelfAttention: out = softmax((xWq)(xWk)^T / sqrt(d)) (xWv)
// B=4, S=2048, D=1024, fp32 in/out.
//
// Precision: f16 hi/lo split + 3-product MFMA for xWq, xWk, QK^T (softmax is
// near-one-hot; S must be ~fp32-accurate). Plain f16 MFMA for V^T and PV.
//
// R1: LDS chunk swizzle -> bank conflicts 8.4M -> 0.
// R2: dispatch fusion (QK proj fused, V^T as direct GEMM, weight prep merged).
// R3: MFMA 32x32x16.
// R5: swizzle fix f(r)=((r>>1)+(r>>4))&3 -> conflicts 0; dur unchanged ->
//   latency stall diagnosis (no pipe saturated).
// R6: register-staging pipeline -> 999us REGRESSION. Root cause per counters:
//   WRITE_SIZE 65MB -> 844-940MB (scratch), VGPR_Count capped at 92 ->
//   compiler spilled st[] to scratch. Pipeline never actually tested.
// R7: same pipeline + __launch_bounds__(256, 2): per-wave budget 256 unified
//   VGPR+AGPR, our ~150-180 fits -> no spill. 2 blocks/CU matches R5's
//   measured effective occupancy, so nothing is lost.

typedef _Float16 half8 __attribute__((ext_vector_type(8)));
typedef _Float16 half4v __attribute__((ext_vector_type(4)));
typedef float f32x16 __attribute__((ext_vector_type(16)));

// ---------------------------------------------------------------------------
// NT GEMM: C[M,N] = (A0+A1)[M,K] * (B0+B1)[N,K]^T   (A,B row-major, K inner)
// NPROD: 1 = single product (A0*B0), 3 = split product (A0B0+A0B1+A1B0)
// OUTMODE: 0 = fp32 to Cf; 1 = f16 hi/lo split to C0,C1; 2 = f16 to C0
// Per-block scale: blocks in lower half of gridDim.y use `scale`, else scale2.
// Tiles: 128x128 per block (256 thr = 4 waves, 64x64 per wave), BK=32.
// mfma_f32_32x32x16_f16 fragments:
//   A/B frag: row/col = lane&31, 8 contiguous k at (lane>>5)*8
//   C/D frag: col = lane&31, row = (reg&3) + 8*(reg>>2) + 4*(lane>>5)
// LDS swizzle: physical 16B chunk p of row r holds logical chunk
//   c = (p - f(r)) & 3 with f(r) = ((r>>1) + (r>>4)) & 3.
// K-loop: register-staging pipeline -- tile k+1 loads into VGPRs during the
// compute of tile k; ds_write commits at the top of the next iter, so the
// vmcnt wait lands after a full compute phase (latency hidden).
// ---------------------------------------------------------------------------
template <int NPROD, int OUTMODE>
__global__ __launch_bounds__(256, 2) void gemm_nt(
    const _Float16* __restrict__ A0, const _Float16* __restrict__ A1,
    const _Float16* __restrict__ B0, const _Float16* __restrict__ B1,
    float* __restrict__ Cf, _Float16* __restrict__ C0, _Float16* __restrict__ C1,
    int lda, int ldb, int ldc, int K,
    long sA, long sB, long sC, float scale, float scale2) {
    constexpr int NTILES = (NPROD == 3) ? 4 : 2;
    constexpr int NST = (NPROD == 3) ? 8 : 4;
    __shared__ alignas(16) _Float16 smem[NTILES * 4096];  // [128][32] f16 tiles
    _Float16* sA0 = smem;
    _Float16* sB0 = smem + 4096;
    _Float16* sA1 = (NPROD == 3) ? smem + 8192 : smem;
    _Float16* sB1 = (NPROD == 3) ? smem + 12288 : smem;

    const int tid = threadIdx.x;
    const int wave = tid >> 6, lane = tid & 63;
    const int wm = (wave >> 1) * 64, wn = (wave & 1) * 64;
    const int q2 = lane >> 5, r32 = lane & 31;

    const long zA = (long)blockIdx.z * sA;
    const long zB = (long)blockIdx.z * sB;
    const long zC = (long)blockIdx.z * sC;

    const float sc = (blockIdx.y * 2 < gridDim.y) ? scale : scale2;

    // staging: thread t owns LDS offset t*16 (phys row t>>2, chunk t&3);
    // it fetches logical chunk ((t&3) - f(t>>2)) & 3, f(r)=((r>>1)+(r>>4))&3.
    const int trow = tid >> 2;
    const int tcol = (((tid & 3) - ((tid >> 3) & 3) - ((tid >> 6) & 3)) & 3) * 8;
    const _Float16* gA0 = A0 + zA + (long)(blockIdx.x * 128 + trow) * lda + tcol;
    const _Float16* gB0 = B0 + zB + (long)(blockIdx.y * 128 + trow) * ldb + tcol;
    const _Float16* gA1 = (NPROD == 3) ? (A1 + zA + (long)(blockIdx.x * 128 + trow) * lda + tcol) : nullptr;
    const _Float16* gB1 = (NPROD == 3) ? (B1 + zB + (long)(blockIdx.y * 128 + trow) * ldb + tcol) : nullptr;

    f32x16 acc[2][2];
#pragma unroll
    for (int i = 0; i < 2; ++i)
#pragma unroll
        for (int j = 0; j < 2; ++j)
#pragma unroll
            for (int r = 0; r < 16; ++r) acc[i][j][r] = 0.f;

    const int ldsoff = tid * 8;  // halves; *2B = tid*16 bytes
    // read-side: fragment row = {wm|wn} + 32*i + r32; f(row) reduces exactly to
    // (r32>>1) + (r32>>4) + 2*i (mod 4). Logical chunk = q2 + 2h.
    const int fbase = q2 + (r32 >> 1) + (r32 >> 4);

    // register staging buffer (tile k in flight)
    float4 st[NST];
    {
        st[0] = *(const float4*)gA0;
        st[1] = *(const float4*)(gA0 + 64 * lda);
        st[2] = *(const float4*)gB0;
        st[3] = *(const float4*)(gB0 + 64 * ldb);
        if (NPROD == 3) {
            st[4] = *(const float4*)gA1;
            st[5] = *(const float4*)(gA1 + 64 * lda);
            st[6] = *(const float4*)gB1;
            st[7] = *(const float4*)(gB1 + 64 * ldb);
        }
    }

    for (int k0 = 0; k0 < K; k0 += 32) {
        __syncthreads();  // previous iter's ds_reads done before overwrite
        // commit staged tile to LDS (implicit vmcnt wait happens here, after a
        // full compute phase of latency hiding)
        *(float4*)(sA0 + ldsoff) = st[0];
        *(float4*)(sA0 + ldsoff + 2048) = st[1];
        *(float4*)(sB0 + ldsoff) = st[2];
        *(float4*)(sB0 + ldsoff + 2048) = st[3];
        if (NPROD == 3) {
            *(float4*)(sA1 + ldsoff) = st[4];
            *(float4*)(sA1 + ldsoff + 2048) = st[5];
            *(float4*)(sB1 + ldsoff) = st[6];
            *(float4*)(sB1 + ldsoff + 2048) = st[7];
        }
        __syncthreads();  // tile visible

        // prefetch next tile into regs; lands during the compute below
        gA0 += 32; gB0 += 32;
        if (NPROD == 3) { gA1 += 32; gB1 += 32; }
        if (k0 + 32 < K) {
            st[0] = *(const float4*)gA0;
            st[1] = *(const float4*)(gA0 + 64 * lda);
            st[2] = *(const float4*)gB0;
            st[3] = *(const float4*)(gB0 + 64 * ldb);
            if (NPROD == 3) {
                st[4] = *(const float4*)gA1;
                st[5] = *(const float4*)(gA1 + 64 * lda);
                st[6] = *(const float4*)gB1;
                st[7] = *(const float4*)(gB1 + 64 * ldb);
            }
        }

        // compute in two k-half phases (caps fragment register liveness)
#pragma unroll
        for (int h = 0; h < 2; ++h) {
            half8 a0[2], b0[2], a1[2], b1[2];
#pragma unroll
            for (int i = 0; i < 2; ++i) {
                const int pp = ((fbase + 2 * i + 2 * h) & 3) * 8;
                a0[i] = *(const half8*)(sA0 + (wm + i * 32 + r32) * 32 + pp);
                b0[i] = *(const half8*)(sB0 + (wn + i * 32 + r32) * 32 + pp);
                if (NPROD == 3) {
                    a1[i] = *(const half8*)(sA1 + (wm + i * 32 + r32) * 32 + pp);
                    b1[i] = *(const half8*)(sB1 + (wn + i * 32 + r32) * 32 + pp);
                }
            }
#pragma unroll
            for (int i = 0; i < 2; ++i)
#pragma unroll
                for (int j = 0; j < 2; ++j) {
                    acc[i][j] = __builtin_amdgcn_mfma_f32_32x32x16_f16(a0[i], b0[j], acc[i][j], 0, 0, 0);
                    if (NPROD == 3) {
                        acc[i][j] = __builtin_amdgcn_mfma_f32_32x32x16_f16(a0[i], b1[j], acc[i][j], 0, 0, 0);
                        acc[i][j] = __builtin_amdgcn_mfma_f32_32x32x16_f16(a1[i], b0[j], acc[i][j], 0, 0, 0);
                    }
                }
        }
    }

    // epilogue: C/D layout col=lane&31, row=(reg&3)+8*(reg>>2)+4*q2
    const int crow0 = blockIdx.x * 128 + wm + 4 * q2;
    const int ccol0 = blockIdx.y * 128 + wn + r32;
#pragma unroll
    for (int i = 0; i < 2; ++i)
#pragma unroll
        for (int j = 0; j < 2; ++j)
#pragma unroll
            for (int r = 0; r < 16; ++r) {
                int row = crow0 + i * 32 + (r & 3) + 8 * (r >> 2);
                long off = zC + (long)row * ldc + (ccol0 + j * 32);
                float v = acc[i][j][r] * sc;
                if (OUTMODE == 0) {
                    Cf[off] = v;
                } else if (OUTMODE == 2) {
                    C0[off] = (_Float16)v;
                } else {
                    _Float16 h = (_Float16)v;
                    C0[off] = h;
                    C1[off] = (_Float16)(v - (float)h);
                }
            }
}

// ---------------------------------------------------------------------------
// Fused prep: blocks [0, NSPLIT) do the x fp32 -> f16 hi/lo split (x4 vec);
// blocks [NSPLIT, NSPLIT+3072) transpose+split the three weight matrices.
// Wq^T/Wk^T land stacked in one [2048][1024] buffer.
// ---------------------------------------------------------------------------
__global__ __launch_bounds__(256) void prep_fused(
    const float* __restrict__ x, _Float16* __restrict__ x0, _Float16* __restrict__ x1,
    long n4, int nsplit,
    const float* __restrict__ wq, const float* __restrict__ wk,
    const float* __restrict__ wv,
    _Float16* __restrict__ qk0, _Float16* __restrict__ qk1,
    _Float16* __restrict__ v0, _Float16* __restrict__ v1) {
    __shared__ float t[32][33];
    if ((int)blockIdx.x < nsplit) {
        long i = (long)blockIdx.x * 256 + threadIdx.x;
        if (i >= n4) return;
        float4 v = ((const float4*)x)[i];
        float a[4] = {v.x, v.y, v.z, v.w};
        half4v h, l;
#pragma unroll
        for (int c = 0; c < 4; ++c) {
            h[c] = (_Float16)a[c];
            l[c] = (_Float16)(a[c] - (float)h[c]);
        }
        ((half4v*)x0)[i] = h;
        ((half4v*)x1)[i] = l;
        return;
    }
    const int idx = blockIdx.x - nsplit;        // 0..3071
    const int z = idx >> 10;                    // 0..2
    const int tile = idx & 1023;                // 0..1023
    const float* in = (z == 0) ? wq : (z == 1) ? wk : wv;
    _Float16* o0 = (z == 0) ? qk0 : (z == 1) ? qk0 + 1024 * 1024 : v0;
    _Float16* o1 = (z == 0) ? qk1 : (z == 1) ? qk1 + 1024 * 1024 : v1;

    const int c0 = (tile & 31) * 32, r0 = (tile >> 5) * 32;
    const int tx = threadIdx.x & 31, ty = threadIdx.x >> 5;
#pragma unroll
    for (int i = 0; i < 32; i += 8)
        t[ty + i][tx] = in[(long)(r0 + ty + i) * 1024 + c0 + tx];
    __syncthreads();
#pragma unroll
    for (int i = 0; i < 32; i += 8) {
        float v = t[tx][ty + i];
        _Float16 h = (_Float16)v;
        long o = (long)(c0 + ty + i) * 1024 + r0 + tx;
        o0[o] = h;
        o1[o] = (_Float16)(v - (float)h);
    }
}

// ---------------------------------------------------------------------------
// row softmax: S fp32 [8192][2048] -> P f16, one block per row (vectorized)
// ---------------------------------------------------------------------------
__global__ __launch_bounds__(256) void softmax_rows(const float* __restrict__ S,
                                                    _Float16* __restrict__ P) {
    const int n = 2048;
    const long base = (long)blockIdx.x * n;
    const float4* row4 = (const float4*)(S + base);
    const int tid = threadIdx.x;
    const int wave = tid >> 6;

    float4 v0 = row4[tid * 2];
    float4 v1 = row4[tid * 2 + 1];
    float v[8] = {v0.x, v0.y, v0.z, v0.w, v1.x, v1.y, v1.z, v1.w};
    float lm = -3.4e38f;
#pragma unroll
    for (int t = 0; t < 8; ++t) lm = fmaxf(lm, v[t]);
#pragma unroll
    for (int o = 32; o > 0; o >>= 1) lm = fmaxf(lm, __shfl_xor(lm, o));
    __shared__ float redm[4];
    __shared__ float reds[4];
    if ((tid & 63) == 0) redm[wave] = lm;
    __syncthreads();
    lm = fmaxf(fmaxf(redm[0], redm[1]), fmaxf(redm[2], redm[3]));

    float e[8];
    float ls = 0.f;
#pragma unroll
    for (int t = 0; t < 8; ++t) {
        e[t] = __expf(v[t] - lm);
        ls += e[t];
    }
#pragma unroll
    for (int o = 32; o > 0; o >>= 1) ls += __shfl_xor(ls, o);
    if ((tid & 63) == 0) reds[wave] = ls;
    __syncthreads();
    ls = reds[0] + reds[1] + reds[2] + reds[3];
    const float inv = 1.f / ls;
    half8 p;
#pragma unroll
    for (int t = 0; t < 8; ++t) p[t] = (_Float16)(e[t] * inv);
    ((half8*)(P + base))[tid] = p;
}

// ---------------------------------------------------------------------------
extern "C" void kernel_launch(void* const* d_in, const int* in_sizes, int n_in,
                              void* d_out, int out_size, void* d_ws, size_t ws_size,
                              hipStream_t stream) {
    (void)in_sizes; (void)n_in; (void)out_size; (void)ws_size;
    const float* x = (const float*)d_in[0];
    const float* wq = (const float*)d_in[1];
    const float* wk = (const float*)d_in[2];
    const float* wv = (const float*)d_in[3];
    float* out = (float*)d_out;
    char* ws = (char*)d_ws;

    const long MB = 1l << 20;
    // ws layout (188 MB):
    _Float16* Wqk0 = (_Float16*)(ws + 0 * MB);   // [2048][1024] 4 MB
    _Float16* Wqk1 = (_Float16*)(ws + 4 * MB);   // 4 MB
    _Float16* Wv0  = (_Float16*)(ws + 8 * MB);   // 2 MB
    _Float16* Wv1  = (_Float16*)(ws + 10 * MB);  // 2 MB (unused by NPROD=1 path)
    _Float16* x0   = (_Float16*)(ws + 12 * MB);  // 16 MB
    _Float16* x1   = (_Float16*)(ws + 28 * MB);  // 16 MB
    _Float16* P    = (_Float16*)(ws + 12 * MB);  // 32 MB, reuses dead x0/x1
    _Float16* QK0  = (_Float16*)(ws + 44 * MB);  // [8192][2048] 32 MB
    _Float16* QK1  = (_Float16*)(ws + 76 * MB);  // 32 MB
    _Float16* Vt   = (_Float16*)(ws + 108 * MB); // [1024][8192] 16 MB
    float*    S    = (float*)(ws + 124 * MB);    // 64 MB

    const int B = 4, SEQ = 2048, D = 1024;
    const long M = (long)B * SEQ;  // 8192
    const long ssq = (long)SEQ * SEQ;  // per-batch S stride
    const int nsplit = (int)((M * D / 4 + 255) / 256);  // 8192

    // 1) fused prep: x split + weight transpose/split (one dispatch)
    prep_fused<<<dim3(nsplit + 3072), dim3(256), 0, stream>>>(
        x, x0, x1, M * D / 4, nsplit, wq, wk, wv, Wqk0, Wqk1, Wv0, Wv1);

    // 2) fused Q|K projection: QK[m][n] (n<1024 -> Q/32, n>=1024 -> K), split out
    gemm_nt<3, 1><<<dim3(64, 16, 1), dim3(256), 0, stream>>>(
        x0, x1, Wqk0, Wqk1, nullptr, QK0, QK1, D, D, 2 * D, D,
        0, 0, 0, 0.03125f, 1.0f);

    // 3) V^T directly: Vt[e][m] = sum_d Wv^T[e][d] * x[m][d]  (NT, A=Wv^T, B=x)
    gemm_nt<1, 2><<<dim3(8, 64, 1), dim3(256), 0, stream>>>(
        Wv0, nullptr, x0, nullptr, nullptr, Vt, nullptr, D, D, (int)M, D,
        0, 0, 0, 1.0f, 1.0f);

    // 4) S = Qs @ K^T (fp32, scaling already folded into Q)
    gemm_nt<3, 0><<<dim3(16, 16, B), dim3(256), 0, stream>>>(
        QK0, QK1, QK0 + D, QK1 + D, S, nullptr, nullptr, 2 * D, 2 * D, SEQ, D,
        (long)SEQ * 2 * D, (long)SEQ * 2 * D, ssq, 1.0f, 1.0f);

    // 5) P = rowsoftmax(S) as f16
    softmax_rows<<<dim3(B * SEQ), dim3(256), 0, stream>>>(S, P);

    // 6) out = P @ V = P @ (Vt batch-view)^T ; Vt batch b = cols b*2048..
    gemm_nt<1, 0><<<dim3(16, 8, B), dim3(256), 0, stream>>>(
        P, nullptr, Vt, nullptr, out, nullptr, nullptr, SEQ, (int)M, D, SEQ,
        ssq, (long)SEQ, (long)SEQ * D, 1.0f, 1.0f);
}

// Round 8
// 402.677 us; speedup vs baseline: 2.6074x; 2.6074x over previous
//
#include <hip/hip_runtime.h>
#include <hip/hip_bf16.h>

// HybridSelfAttention: out = softmax((xWq)(xWk)^T / sqrt(d)) (xWv)
// B=4, S=2048, D=1024, fp32 in/out.
//
// Precision: f16 hi/lo split + 3-product MFMA for xWq, xWk, QK^T (softmax is
// near-one-hot; S must be ~fp32-accurate). Plain f16 MFMA for V^T and PV.
//
// R1: LDS chunk swizzle -> bank conflicts 8.4M -> 0.
// R2: dispatch fusion (QK proj fused, V^T direct GEMM, weight prep merged).
// R3: MFMA 32x32x16.
// R5: swizzle fix f(r)=((r>>1)+(r>>4))&3 -> conflicts 0; dur unchanged ->
//   latency-stall diagnosis (MfmaUtil 35 + VALU 11, HBM 21% -- nothing bound).
// R6/R7: register-staging transport -> compiler spilled st[] to scratch both
//   times (WRITE_SIZE 65MB -> 0.84-1.1GB). launch_bounds(256,2) made the
//   allocator SHRINK to 64 VGPR and spill harder. Transport idea dead.
// R8: keep global_load_lds transport (R5), restructure the K-loop instead:
//   double-buffered LDS, ONE barrier per iter. Loads for tile k+1 are issued
//   right after the barrier that drains tile k, so the next barrier's
//   vmcnt(0) waits on loads that have been in flight for a full compute
//   phase. WAR on buf^1 is protected by the intervening barrier.

typedef _Float16 half8 __attribute__((ext_vector_type(8)));
typedef _Float16 half4v __attribute__((ext_vector_type(4)));
typedef float f32x16 __attribute__((ext_vector_type(16)));

#define GLOBAL_AS __attribute__((address_space(1)))
#define LDS_AS __attribute__((address_space(3)))

__device__ __forceinline__ void gll16(const _Float16* g, _Float16* l) {
    // async global->LDS DMA, 16B per lane; LDS dest is wave-uniform base + lane*16
    __builtin_amdgcn_global_load_lds((GLOBAL_AS const void*)g, (LDS_AS void*)l, 16, 0, 0);
}

// ---------------------------------------------------------------------------
// NT GEMM: C[M,N] = (A0+A1)[M,K] * (B0+B1)[N,K]^T   (A,B row-major, K inner)
// NPROD: 1 = single product (A0*B0), 3 = split product (A0B0+A0B1+A1B0)
// OUTMODE: 0 = fp32 to Cf; 1 = f16 hi/lo split to C0,C1; 2 = f16 to C0
// Per-block scale: blocks in lower half of gridDim.y use `scale`, else scale2.
// Tiles: 128x128 per block (256 thr = 4 waves, 64x64 per wave), BK=32.
// mfma_f32_32x32x16_f16 fragments:
//   A/B frag: row/col = lane&31, 8 contiguous k at (lane>>5)*8
//   C/D frag: col = lane&31, row = (reg&3) + 8*(reg>>2) + 4*(lane>>5)
// LDS swizzle: physical 16B chunk p of row r holds logical chunk
//   c = (p - f(r)) & 3 with f(r) = ((r>>1) + (r>>4)) & 3  (conflict-free,
//   measured 0 in R5).
// ---------------------------------------------------------------------------
template <int NPROD, int OUTMODE>
__global__ __launch_bounds__(256) void gemm_nt(
    const _Float16* __restrict__ A0, const _Float16* __restrict__ A1,
    const _Float16* __restrict__ B0, const _Float16* __restrict__ B1,
    float* __restrict__ Cf, _Float16* __restrict__ C0, _Float16* __restrict__ C1,
    int lda, int ldb, int ldc, int K,
    long sA, long sB, long sC, float scale, float scale2) {
    constexpr int NTILES = (NPROD == 3) ? 4 : 2;
    constexpr int BUFH = NTILES * 4096;  // halves per buffer set
    __shared__ alignas(16) _Float16 smem[2 * BUFH];  // double-buffered tile sets

    const int tid = threadIdx.x;
    const int wave = tid >> 6, lane = tid & 63;
    const int wm = (wave >> 1) * 64, wn = (wave & 1) * 64;
    const int q2 = lane >> 5, r32 = lane & 31;

    const long zA = (long)blockIdx.z * sA;
    const long zB = (long)blockIdx.z * sB;
    const long zC = (long)blockIdx.z * sC;

    const float sc = (blockIdx.y * 2 < gridDim.y) ? scale : scale2;

    // staging: thread t owns LDS offset t*16 within each tile (phys row t>>2,
    // chunk t&3); it fetches logical chunk ((t&3) - f(t>>2)) & 3.
    const int trow = tid >> 2;
    const int tcol = (((tid & 3) - ((tid >> 3) & 3) - ((tid >> 6) & 3)) & 3) * 8;
    const _Float16* gA0 = A0 + zA + (long)(blockIdx.x * 128 + trow) * lda + tcol;
    const _Float16* gB0 = B0 + zB + (long)(blockIdx.y * 128 + trow) * ldb + tcol;
    const _Float16* gA1 = (NPROD == 3) ? (A1 + zA + (long)(blockIdx.x * 128 + trow) * lda + tcol) : nullptr;
    const _Float16* gB1 = (NPROD == 3) ? (B1 + zB + (long)(blockIdx.y * 128 + trow) * ldb + tcol) : nullptr;

    f32x16 acc[2][2];
#pragma unroll
    for (int i = 0; i < 2; ++i)
#pragma unroll
        for (int j = 0; j < 2; ++j)
#pragma unroll
            for (int r = 0; r < 16; ++r) acc[i][j][r] = 0.f;

    const int ldsoff = tid * 8;  // halves; *2B = tid*16 bytes
    // read-side: fragment row = {wm|wn} + 32*i + r32; f(row) reduces exactly to
    // (r32>>1) + (r32>>4) + 2*i (mod 4). Logical chunk = q2 + 2h.
    const int fbase = q2 + (r32 >> 1) + (r32 >> 4);

    // issue tile 0 into buffer 0; pointers then track the NEXT tile to load
    {
        _Float16* s = smem;
        gll16(gA0, s + ldsoff);
        gll16(gA0 + 64 * lda, s + ldsoff + 2048);
        gll16(gB0, s + 4096 + ldsoff);
        gll16(gB0 + 64 * ldb, s + 4096 + ldsoff + 2048);
        if (NPROD == 3) {
            gll16(gA1, s + 8192 + ldsoff);
            gll16(gA1 + 64 * lda, s + 8192 + ldsoff + 2048);
            gll16(gB1, s + 12288 + ldsoff);
            gll16(gB1 + 64 * ldb, s + 12288 + ldsoff + 2048);
        }
        gA0 += 32; gB0 += 32;
        if (NPROD == 3) { gA1 += 32; gB1 += 32; }
    }

    int buf = 0;
    for (int k0 = 0; k0 < K; k0 += 32) {
        __syncthreads();  // drains tile-k loads (in flight a full compute phase)

        // issue tile k+1 into the other buffer; lands during compute below
        if (k0 + 32 < K) {
            _Float16* s = smem + (buf ^ 1) * BUFH;
            gll16(gA0, s + ldsoff);
            gll16(gA0 + 64 * lda, s + ldsoff + 2048);
            gll16(gB0, s + 4096 + ldsoff);
            gll16(gB0 + 64 * ldb, s + 4096 + ldsoff + 2048);
            if (NPROD == 3) {
                gll16(gA1, s + 8192 + ldsoff);
                gll16(gA1 + 64 * lda, s + 8192 + ldsoff + 2048);
                gll16(gB1, s + 12288 + ldsoff);
                gll16(gB1 + 64 * ldb, s + 12288 + ldsoff + 2048);
            }
            gA0 += 32; gB0 += 32;
            if (NPROD == 3) { gA1 += 32; gB1 += 32; }
        }

        // compute tile k from current buffer
        _Float16* sA0 = smem + buf * BUFH;
        _Float16* sB0 = sA0 + 4096;
        _Float16* sA1 = (NPROD == 3) ? sA0 + 8192 : sA0;
        _Float16* sB1 = (NPROD == 3) ? sA0 + 12288 : sA0;
#pragma unroll
        for (int h = 0; h < 2; ++h) {
            half8 a0[2], b0[2], a1[2], b1[2];
#pragma unroll
            for (int i = 0; i < 2; ++i) {
                const int pp = ((fbase + 2 * i + 2 * h) & 3) * 8;
                a0[i] = *(const half8*)(sA0 + (wm + i * 32 + r32) * 32 + pp);
                b0[i] = *(const half8*)(sB0 + (wn + i * 32 + r32) * 32 + pp);
                if (NPROD == 3) {
                    a1[i] = *(const half8*)(sA1 + (wm + i * 32 + r32) * 32 + pp);
                    b1[i] = *(const half8*)(sB1 + (wn + i * 32 + r32) * 32 + pp);
                }
            }
#pragma unroll
            for (int i = 0; i < 2; ++i)
#pragma unroll
                for (int j = 0; j < 2; ++j) {
                    acc[i][j] = __builtin_amdgcn_mfma_f32_32x32x16_f16(a0[i], b0[j], acc[i][j], 0, 0, 0);
                    if (NPROD == 3) {
                        acc[i][j] = __builtin_amdgcn_mfma_f32_32x32x16_f16(a0[i], b1[j], acc[i][j], 0, 0, 0);
                        acc[i][j] = __builtin_amdgcn_mfma_f32_32x32x16_f16(a1[i], b0[j], acc[i][j], 0, 0, 0);
                    }
                }
        }
        buf ^= 1;
    }

    // epilogue: C/D layout col=lane&31, row=(reg&3)+8*(reg>>2)+4*q2
    const int crow0 = blockIdx.x * 128 + wm + 4 * q2;
    const int ccol0 = blockIdx.y * 128 + wn + r32;
#pragma unroll
    for (int i = 0; i < 2; ++i)
#pragma unroll
        for (int j = 0; j < 2; ++j)
#pragma unroll
            for (int r = 0; r < 16; ++r) {
                int row = crow0 + i * 32 + (r & 3) + 8 * (r >> 2);
                long off = zC + (long)row * ldc + (ccol0 + j * 32);
                float v = acc[i][j][r] * sc;
                if (OUTMODE == 0) {
                    Cf[off] = v;
                } else if (OUTMODE == 2) {
                    C0[off] = (_Float16)v;
                } else {
                    _Float16 h = (_Float16)v;
                    C0[off] = h;
                    C1[off] = (_Float16)(v - (float)h);
                }
            }
}

// ---------------------------------------------------------------------------
// Fused prep: blocks [0, NSPLIT) do the x fp32 -> f16 hi/lo split (x4 vec);
// blocks [NSPLIT, NSPLIT+3072) transpose+split the three weight matrices.
// Wq^T/Wk^T land stacked in one [2048][1024] buffer.
// ---------------------------------------------------------------------------
__global__ __launch_bounds__(256) void prep_fused(
    const float* __restrict__ x, _Float16* __restrict__ x0, _Float16* __restrict__ x1,
    long n4, int nsplit,
    const float* __restrict__ wq, const float* __restrict__ wk,
    const float* __restrict__ wv,
    _Float16* __restrict__ qk0, _Float16* __restrict__ qk1,
    _Float16* __restrict__ v0, _Float16* __restrict__ v1) {
    __shared__ float t[32][33];
    if ((int)blockIdx.x < nsplit) {
        long i = (long)blockIdx.x * 256 + threadIdx.x;
        if (i >= n4) return;
        float4 v = ((const float4*)x)[i];
        float a[4] = {v.x, v.y, v.z, v.w};
        half4v h, l;
#pragma unroll
        for (int c = 0; c < 4; ++c) {
            h[c] = (_Float16)a[c];
            l[c] = (_Float16)(a[c] - (float)h[c]);
        }
        ((half4v*)x0)[i] = h;
        ((half4v*)x1)[i] = l;
        return;
    }
    const int idx = blockIdx.x - nsplit;        // 0..3071
    const int z = idx >> 10;                    // 0..2
    const int tile = idx & 1023;                // 0..1023
    const float* in = (z == 0) ? wq : (z == 1) ? wk : wv;
    _Float16* o0 = (z == 0) ? qk0 : (z == 1) ? qk0 + 1024 * 1024 : v0;
    _Float16* o1 = (z == 0) ? qk1 : (z == 1) ? qk1 + 1024 * 1024 : v1;

    const int c0 = (tile & 31) * 32, r0 = (tile >> 5) * 32;
    const int tx = threadIdx.x & 31, ty = threadIdx.x >> 5;
#pragma unroll
    for (int i = 0; i < 32; i += 8)
        t[ty + i][tx] = in[(long)(r0 + ty + i) * 1024 + c0 + tx];
    __syncthreads();
#pragma unroll
    for (int i = 0; i < 32; i += 8) {
        float v = t[tx][ty + i];
        _Float16 h = (_Float16)v;
        long o = (long)(c0 + ty + i) * 1024 + r0 + tx;
        o0[o] = h;
        o1[o] = (_Float16)(v - (float)h);
    }
}

// ---------------------------------------------------------------------------
// row softmax: S fp32 [8192][2048] -> P f16, one block per row (vectorized)
// ---------------------------------------------------------------------------
__global__ __launch_bounds__(256) void softmax_rows(const float* __restrict__ S,
                                                    _Float16* __restrict__ P) {
    const int n = 2048;
    const long base = (long)blockIdx.x * n;
    const float4* row4 = (const float4*)(S + base);
    const int tid = threadIdx.x;
    const int wave = tid >> 6;

    float4 v0 = row4[tid * 2];
    float4 v1 = row4[tid * 2 + 1];
    float v[8] = {v0.x, v0.y, v0.z, v0.w, v1.x, v1.y, v1.z, v1.w};
    float lm = -3.4e38f;
#pragma unroll
    for (int t = 0; t < 8; ++t) lm = fmaxf(lm, v[t]);
#pragma unroll
    for (int o = 32; o > 0; o >>= 1) lm = fmaxf(lm, __shfl_xor(lm, o));
    __shared__ float redm[4];
    __shared__ float reds[4];
    if ((tid & 63) == 0) redm[wave] = lm;
    __syncthreads();
    lm = fmaxf(fmaxf(redm[0], redm[1]), fmaxf(redm[2], redm[3]));

    float e[8];
    float ls = 0.f;
#pragma unroll
    for (int t = 0; t < 8; ++t) {
        e[t] = __expf(v[t] - lm);
        ls += e[t];
    }
#pragma unroll
    for (int o = 32; o > 0; o >>= 1) ls += __shfl_xor(ls, o);
    if ((tid & 63) == 0) reds[wave] = ls;
    __syncthreads();
    ls = reds[0] + reds[1] + reds[2] + reds[3];
    const float inv = 1.f / ls;
    half8 p;
#pragma unroll
    for (int t = 0; t < 8; ++t) p[t] = (_Float16)(e[t] * inv);
    ((half8*)(P + base))[tid] = p;
}

// ---------------------------------------------------------------------------
extern "C" void kernel_launch(void* const* d_in, const int* in_sizes, int n_in,
                              void* d_out, int out_size, void* d_ws, size_t ws_size,
                              hipStream_t stream) {
    (void)in_sizes; (void)n_in; (void)out_size; (void)ws_size;
    const float* x = (const float*)d_in[0];
    const float* wq = (const float*)d_in[1];
    const float* wk = (const float*)d_in[2];
    const float* wv = (const float*)d_in[3];
    float* out = (float*)d_out;
    char* ws = (char*)d_ws;

    const long MB = 1l << 20;
    // ws layout (188 MB):
    _Float16* Wqk0 = (_Float16*)(ws + 0 * MB);   // [2048][1024] 4 MB
    _Float16* Wqk1 = (_Float16*)(ws + 4 * MB);   // 4 MB
    _Float16* Wv0  = (_Float16*)(ws + 8 * MB);   // 2 MB
    _Float16* Wv1  = (_Float16*)(ws + 10 * MB);  // 2 MB (unused by NPROD=1 path)
    _Float16* x0   = (_Float16*)(ws + 12 * MB);  // 16 MB
    _Float16* x1   = (_Float16*)(ws + 28 * MB);  // 16 MB
    _Float16* P    = (_Float16*)(ws + 12 * MB);  // 32 MB, reuses dead x0/x1
    _Float16* QK0  = (_Float16*)(ws + 44 * MB);  // [8192][2048] 32 MB
    _Float16* QK1  = (_Float16*)(ws + 76 * MB);  // 32 MB
    _Float16* Vt   = (_Float16*)(ws + 108 * MB); // [1024][8192] 16 MB
    float*    S    = (float*)(ws + 124 * MB);    // 64 MB

    const int B = 4, SEQ = 2048, D = 1024;
    const long M = (long)B * SEQ;  // 8192
    const long ssq = (long)SEQ * SEQ;  // per-batch S stride
    const int nsplit = (int)((M * D / 4 + 255) / 256);  // 8192

    // 1) fused prep: x split + weight transpose/split (one dispatch)
    prep_fused<<<dim3(nsplit + 3072), dim3(256), 0, stream>>>(
        x, x0, x1, M * D / 4, nsplit, wq, wk, wv, Wqk0, Wqk1, Wv0, Wv1);

    // 2) fused Q|K projection: QK[m][n] (n<1024 -> Q/32, n>=1024 -> K), split out
    gemm_nt<3, 1><<<dim3(64, 16, 1), dim3(256), 0, stream>>>(
        x0, x1, Wqk0, Wqk1, nullptr, QK0, QK1, D, D, 2 * D, D,
        0, 0, 0, 0.03125f, 1.0f);

    // 3) V^T directly: Vt[e][m] = sum_d Wv^T[e][d] * x[m][d]  (NT, A=Wv^T, B=x)
    gemm_nt<1, 2><<<dim3(8, 64, 1), dim3(256), 0, stream>>>(
        Wv0, nullptr, x0, nullptr, nullptr, Vt, nullptr, D, D, (int)M, D,
        0, 0, 0, 1.0f, 1.0f);

    // 4) S = Qs @ K^T (fp32, scaling already folded into Q)
    gemm_nt<3, 0><<<dim3(16, 16, B), dim3(256), 0, stream>>>(
        QK0, QK1, QK0 + D, QK1 + D, S, nullptr, nullptr, 2 * D, 2 * D, SEQ, D,
        (long)SEQ * 2 * D, (long)SEQ * 2 * D, ssq, 1.0f, 1.0f);

    // 5) P = rowsoftmax(S) as f16
    softmax_rows<<<dim3(B * SEQ), dim3(256), 0, stream>>>(S, P);

    // 6) out = P @ V = P @ (Vt batch-view)^T ; Vt batch b = cols b*2048..
    gemm_nt<1, 0><<<dim3(16, 8, B), dim3(256), 0, stream>>>(
        P, nullptr, Vt, nullptr, out, nullptr, nullptr, SEQ, (int)M, D, SEQ,
        ssq, (long)SEQ, (long)SEQ * D, 1.0f, 1.0f);
}